// Round 1
// baseline (517.917 us; speedup 1.0000x reference)
//
#include <hip/hip_runtime.h>

// LayerNorm backward: B=4, S=4096, H=2048, fp32.
// Outputs concatenated: dx [B*S*H] ++ dgamma [H] ++ dbeta [H].

constexpr int Bc = 4, Sc = 4096, Hc = 2048;
constexpr int ROWS = Bc * Sc;        // 16384
constexpr int THREADS = 256;         // 4 waves; each thread owns 8 columns
constexpr int RPB = 32;              // rows per block
constexpr int NBLK = ROWS / RPB;     // 512 blocks -> 8 waves/CU

__device__ __forceinline__ void load8(const float* __restrict__ p, int c0, int c1, float v[8]) {
    float4 a = *(const float4*)(p + c0);
    float4 b = *(const float4*)(p + c1);
    v[0] = a.x; v[1] = a.y; v[2] = a.z; v[3] = a.w;
    v[4] = b.x; v[5] = b.y; v[6] = b.z; v[7] = b.w;
}

__device__ __forceinline__ void store8(float* __restrict__ p, int c0, int c1, const float v[8]) {
    float4 a = {v[0], v[1], v[2], v[3]};
    float4 b = {v[4], v[5], v[6], v[7]};
    *(float4*)(p + c0) = a;
    *(float4*)(p + c1) = b;
}

__global__ __launch_bounds__(THREADS) void ln_bwd_kernel(
    const float* __restrict__ dy, const float* __restrict__ x1,
    const float* __restrict__ x2, const float* __restrict__ rstd,
    const float* __restrict__ mean, const float* __restrict__ gamma,
    const float* __restrict__ dsum, float* __restrict__ out)
{
    float* out_x = out;
    float* out_g = out + (size_t)ROWS * Hc;
    float* out_b = out_g + Hc;

    const int t   = threadIdx.x;
    const int wid = t >> 6;                 // wave id (wave = 64 lanes)
    const int c0  = t * 4;                  // first float4 segment
    const int c1  = (Hc / 2) + t * 4;       // second float4 segment

    __shared__ float red[4][3];

    float g[8];
    {
        float4 a = *(const float4*)(gamma + c0);
        float4 b = *(const float4*)(gamma + c1);
        g[0] = a.x; g[1] = a.y; g[2] = a.z; g[3] = a.w;
        g[4] = b.x; g[5] = b.y; g[6] = b.z; g[7] = b.w;
    }

    float dg[8], db[8];
    #pragma unroll
    for (int i = 0; i < 8; ++i) { dg[i] = 0.f; db[i] = 0.f; }

    const int row0 = blockIdx.x * RPB;
    const float inv_d = 1.0f / (float)Hc;

    for (int r = 0; r < RPB; ++r) {
        const int row = row0 + r;
        const size_t base = (size_t)row * Hc;
        const float mu = mean[row];
        const float rs = rstd[row];

        float dyv[8], xh[8], p[8];
        load8(dy + base, c0, c1, dyv);
        {
            float av[8], bv[8];
            load8(x1 + base, c0, c1, av);
            load8(x2 + base, c0, c1, bv);
            #pragma unroll
            for (int i = 0; i < 8; ++i) xh[i] = av[i] + bv[i] - mu;
        }
        #pragma unroll
        for (int i = 0; i < 8; ++i) p[i] = dyv[i] * g[i];

        // Three row sums: S1 = sum(p*xh), S2 = sum(p), S3 = sum(xh)
        float s1 = 0.f, s2 = 0.f, s3 = 0.f;
        #pragma unroll
        for (int i = 0; i < 8; ++i) { s1 += p[i] * xh[i]; s2 += p[i]; s3 += xh[i]; }

        #pragma unroll
        for (int off = 32; off > 0; off >>= 1) {
            s1 += __shfl_xor(s1, off);
            s2 += __shfl_xor(s2, off);
            s3 += __shfl_xor(s3, off);
        }
        if ((t & 63) == 0) { red[wid][0] = s1; red[wid][1] = s2; red[wid][2] = s3; }
        __syncthreads();
        const float S1 = red[0][0] + red[1][0] + red[2][0] + red[3][0];
        const float S2 = red[0][1] + red[1][1] + red[2][1] + red[3][1];
        const float S3 = red[0][2] + red[1][2] + red[2][2] + red[3][2];
        __syncthreads();   // WAR: protect red[] before next row overwrites

        const float pd_var  = -0.5f * rs * rs * rs * S1;
        const float pd_mean = -rs * S2 - 2.0f * inv_d * pd_var * S3;
        const float k2 = 2.0f * inv_d * pd_var;
        const float km = inv_d * pd_mean;

        float ds[8], o[8];
        load8(dsum + base, c0, c1, ds);
        #pragma unroll
        for (int i = 0; i < 8; ++i) o[i] = p[i] * rs + k2 * xh[i] + km + ds[i];
        store8(out_x + base, c0, c1, o);

        // param-grad partials (columns are thread-owned -> register accumulate)
        #pragma unroll
        for (int i = 0; i < 8; ++i) { dg[i] += dyv[i] * xh[i] * rs; db[i] += dyv[i]; }
    }

    // One atomic per column per block: 512 adds/address total.
    #pragma unroll
    for (int i = 0; i < 4; ++i) atomicAdd(out_g + c0 + i, dg[i]);
    #pragma unroll
    for (int i = 0; i < 4; ++i) atomicAdd(out_g + c1 + i, dg[4 + i]);
    #pragma unroll
    for (int i = 0; i < 4; ++i) atomicAdd(out_b + c0 + i, db[i]);
    #pragma unroll
    for (int i = 0; i < 4; ++i) atomicAdd(out_b + c1 + i, db[4 + i]);
}

extern "C" void kernel_launch(void* const* d_in, const int* in_sizes, int n_in,
                              void* d_out, int out_size, void* d_ws, size_t ws_size,
                              hipStream_t stream) {
    const float* dy    = (const float*)d_in[0];
    const float* x1    = (const float*)d_in[1];
    const float* x2    = (const float*)d_in[2];
    const float* rstd  = (const float*)d_in[3];
    const float* mean  = (const float*)d_in[4];
    const float* gamma = (const float*)d_in[5];
    const float* dsum  = (const float*)d_in[6];
    float* out = (float*)d_out;

    // Zero dgamma/dbeta region (d_out is poisoned 0xAA before every launch).
    hipMemsetAsync(out + (size_t)ROWS * Hc, 0, 2 * Hc * sizeof(float), stream);

    ln_bwd_kernel<<<NBLK, THREADS, 0, stream>>>(dy, x1, x2, rstd, mean, gamma, dsum, out);
}